// Round 11
// baseline (244.304 us; speedup 1.0000x reference)
//
#include <hip/hip_runtime.h>
#include <hip/hip_bf16.h>
#include <hip/hip_fp16.h>

#define N_NODES 50000
#define N_EDGES 800000
#define CH 64
#define N_GRAPHS 256
#define NBUCK 196            // ceil(50000/256); bucket = dst >> 8
#define CHUNK 2048           // edges staged per bin_scatter block
#define NHIST 98             // edge_hist blocks (partial histograms)

__device__ __forceinline__ unsigned bf16_rne(float f) {
    unsigned u = __float_as_uint(f);
    return (u + 0x7fffu + ((u >> 16) & 1u)) >> 16;
}
__device__ __forceinline__ float4 ldtab(const unsigned short* __restrict__ tab, int s, int c4) {
    uint2 u = *(const uint2*)(tab + ((size_t)s << 6) + c4);
    float4 r;
    r.x = __uint_as_float(u.x << 16);
    r.y = __uint_as_float(u.x & 0xffff0000u);
    r.z = __uint_as_float(u.y << 16);
    r.w = __uint_as_float(u.y & 0xffff0000u);
    return r;
}
__device__ __forceinline__ unsigned pack_sn(int s, float n) {
    return (unsigned)s | ((unsigned)__half_as_ushort(__float2half_rn(n)) << 16);
}
__device__ __forceinline__ float unpack_n(unsigned p) {
    return __half2float(__ushort_as_half((unsigned short)(p >> 16)));
}

// ---------------- pass A: per-block partial histograms ----------------
__global__ void edge_hist(const int* __restrict__ ei, int* __restrict__ hpart) {
    __shared__ int h[NBUCK];
    for (int i = threadIdx.x; i < NBUCK; i += 256) h[i] = 0;
    __syncthreads();
    int t = blockIdx.x * 256 + threadIdx.x;
    int stride = NHIST * 256 * 4;
    for (int e = t * 4; e < N_EDGES; e += stride) {
        int4 d = *(const int4*)&ei[N_EDGES + e];
        atomicAdd(&h[d.x >> 8], 1);
        atomicAdd(&h[d.y >> 8], 1);
        atomicAdd(&h[d.z >> 8], 1);
        atomicAdd(&h[d.w >> 8], 1);
    }
    __syncthreads();
    for (int i = threadIdx.x; i < NBUCK; i += 256)
        hpart[blockIdx.x * NBUCK + i] = h[i];
}

// ---------------- pass B: sum partials + bucket scan (+ POOL/CNT zero) ----------------
__global__ void bucket_scan(const int* __restrict__ hpart, int* __restrict__ bstart,
                            int* __restrict__ gcur, float* __restrict__ poolz) {
    int i = blockIdx.x * 256 + threadIdx.x;
    if (i < N_GRAPHS * CH + N_GRAPHS) poolz[i] = 0.0f;
    if (blockIdx.x != 0) return;
    __shared__ int sc[256];
    int tid = threadIdx.x;
    int v = 0;
    if (tid < NBUCK)
        for (int r = 0; r < NHIST; ++r) v += hpart[r * NBUCK + tid];
    sc[tid] = v;
    __syncthreads();
    for (int off = 1; off < 256; off <<= 1) {
        int t = (tid >= off) ? sc[tid - off] : 0;
        __syncthreads();
        sc[tid] += t;
        __syncthreads();
    }
    if (tid < NBUCK) {
        int ex = sc[tid] - v;
        bstart[tid] = ex;
        gcur[tid] = ex;
    }
    if (tid == 255) bstart[NBUCK] = sc[255];   // == N_EDGES
}

// ---------------- pass C: LDS-binned scatter into bucket-sorted EBUF (packed uint) --------
// packed edge: src(16b) | dstlow(8b)<<16 | bucket(8b)<<24
__global__ __launch_bounds__(256) void bin_scatter(const int* __restrict__ ei,
                                                   int* __restrict__ gcur,
                                                   unsigned* __restrict__ ebuf) {
    __shared__ int hist[NBUCK];
    __shared__ int lofs[NBUCK];
    __shared__ int gbase[NBUCK];
    __shared__ int cur[NBUCK];
    __shared__ int sc[256];
    __shared__ unsigned stage[CHUNK];     // 8KB
    int tid = threadIdx.x;
    for (int i = tid; i < NBUCK; i += 256) hist[i] = 0;
    __syncthreads();
    int e0 = blockIdx.x * CHUNK;
    int n = min(CHUNK, N_EDGES - e0);
    int src[8], dst[8];
#pragma unroll
    for (int k = 0; k < 8; ++k) {
        int idx = k * 256 + tid;
        if (idx < n) {
            int e = e0 + idx;
            src[k] = ei[e];
            dst[k] = ei[N_EDGES + e];
            atomicAdd(&hist[dst[k] >> 8], 1);
        } else dst[k] = -1;
    }
    __syncthreads();
    int v = (tid < NBUCK) ? hist[tid] : 0;
    sc[tid] = v;
    __syncthreads();
    for (int off = 1; off < 256; off <<= 1) {
        int t = (tid >= off) ? sc[tid - off] : 0;
        __syncthreads();
        sc[tid] += t;
        __syncthreads();
    }
    if (tid < NBUCK) {
        int ex = sc[tid] - v;
        lofs[tid] = ex;
        cur[tid] = ex;
        gbase[tid] = v ? atomicAdd(&gcur[tid], v) : 0;
    }
    __syncthreads();
#pragma unroll
    for (int k = 0; k < 8; ++k) {
        if (dst[k] >= 0) {
            int b = dst[k] >> 8;
            int p = atomicAdd(&cur[b], 1);
            stage[p] = (unsigned)src[k] | ((unsigned)(dst[k] & 255) << 16)
                                        | ((unsigned)b << 24);
        }
    }
    __syncthreads();
    for (int i = tid; i < n; i += 256) {
        unsigned p = stage[i];
        int b = p >> 24;
        ebuf[gbase[b] + (i - lofs[b])] = p;     // contiguous runs per bucket
    }
}

// ---------------- pass D: per-bucket CSR build (deg, rowp, dinv, col) ----------------
__global__ void csr_bucket(const unsigned* __restrict__ ebuf, const int* __restrict__ bstart,
                           int* __restrict__ deg, int* __restrict__ rowp,
                           float* __restrict__ dinv, int* __restrict__ col) {
    __shared__ int nd[256];
    __shared__ int cur[256];
    __shared__ int sc[256];
    int b = blockIdx.x;
    int tid = threadIdx.x;
    nd[tid] = 0;
    __syncthreads();
    int es = bstart[b], ee = bstart[b + 1];
    for (int e = es + tid; e < ee; e += 256)
        atomicAdd(&nd[(ebuf[e] >> 16) & 255], 1);
    __syncthreads();
    int v = nd[tid];
    sc[tid] = v;
    __syncthreads();
    for (int off = 1; off < 256; off <<= 1) {
        int t = (tid >= off) ? sc[tid - off] : 0;
        __syncthreads();
        sc[tid] += t;
        __syncthreads();
    }
    int node = b * 256 + tid;
    int lstart = es + sc[tid] - v;
    if (node < N_NODES) {
        deg[node] = v;
        rowp[node] = lstart;
        dinv[node] = rsqrtf((float)v + 1.0f);
    }
    cur[tid] = lstart;
    __syncthreads();
    for (int e = es + tid; e < ee; e += 256) {
        unsigned p = ebuf[e];
        int pos = atomicAdd(&cur[(p >> 16) & 255], 1);
        col[pos] = (int)(p & 0xFFFFu);
    }
}

// ---------------- register-blocked GEMM -> bf16 out (f32 or bf16 input) ----------------
// wave = 8 rows (wave-uniform base -> scalar loads); W^T in LDS stride 68
template <int IN_BF16>
__global__ void gemm_reg(const void* __restrict__ inv, const float* __restrict__ W,
                         unsigned short* __restrict__ out, int n) {
    __shared__ float WT[64 * 68];
    int tid = threadIdx.x;
    for (int i = tid; i < 64 * 64; i += 256) {
        int k = i >> 6, c = i & 63;
        WT[c * 68 + k] = W[i];
    }
    __syncthreads();
    int lane = tid & 63;
    int wv = __builtin_amdgcn_readfirstlane(tid >> 6);
    int row0 = blockIdx.x * 32 + wv * 8;
    if (row0 >= n) return;
    float acc[8] = {0.f, 0.f, 0.f, 0.f, 0.f, 0.f, 0.f, 0.f};
    if (IN_BF16) {
        const unsigned short* in = (const unsigned short*)inv;
#pragma unroll 2
        for (int k = 0; k < 64; k += 8) {
            float4 w0 = *(const float4*)&WT[lane * 68 + k];
            float4 w1 = *(const float4*)&WT[lane * 68 + k + 4];
#pragma unroll
            for (int r = 0; r < 8; ++r) {
                uint4 xb = *(const uint4*)&in[(size_t)(row0 + r) * 64 + k]; // scalar 16B = 8 bf16
                acc[r] = fmaf(__uint_as_float(xb.x << 16),         w0.x, acc[r]);
                acc[r] = fmaf(__uint_as_float(xb.x & 0xffff0000u), w0.y, acc[r]);
                acc[r] = fmaf(__uint_as_float(xb.y << 16),         w0.z, acc[r]);
                acc[r] = fmaf(__uint_as_float(xb.y & 0xffff0000u), w0.w, acc[r]);
                acc[r] = fmaf(__uint_as_float(xb.z << 16),         w1.x, acc[r]);
                acc[r] = fmaf(__uint_as_float(xb.z & 0xffff0000u), w1.y, acc[r]);
                acc[r] = fmaf(__uint_as_float(xb.w << 16),         w1.z, acc[r]);
                acc[r] = fmaf(__uint_as_float(xb.w & 0xffff0000u), w1.w, acc[r]);
            }
        }
    } else {
        const float* in = (const float*)inv;
#pragma unroll 2
        for (int k = 0; k < 64; k += 4) {
            float4 w = *(const float4*)&WT[lane * 68 + k];
#pragma unroll
            for (int r = 0; r < 8; ++r) {
                float4 xv = *(const float4*)&in[(size_t)(row0 + r) * 64 + k]; // scalar load
                acc[r] = fmaf(xv.x, w.x, acc[r]);
                acc[r] = fmaf(xv.y, w.y, acc[r]);
                acc[r] = fmaf(xv.z, w.z, acc[r]);
                acc[r] = fmaf(xv.w, w.w, acc[r]);
            }
        }
    }
#pragma unroll
    for (int r = 0; r < 8; ++r)
        out[(size_t)(row0 + r) * 64 + lane] = (unsigned short)bf16_rne(acc[r]);
}

// ---------------- fused aggregation, float4-quad form, 16 edges in flight ----------------
// wave = 1 node; lane l: edge slot q=l>>4, channel quad c4=(l&15)*4
template <int OUT_BF16, int USE_PCK, int WRITE_PCK>
__global__ void agg_v4(const int* __restrict__ rowp, const int* __restrict__ deg,
                       const int* __restrict__ col, const float* __restrict__ dinv,
                       unsigned* __restrict__ pck,
                       const unsigned short* __restrict__ tab, const float* __restrict__ bias,
                       void* __restrict__ outv, int do_relu) {
    int wv = __builtin_amdgcn_readfirstlane(threadIdx.x >> 6);
    int node = blockIdx.x * 4 + wv;
    int lane = threadIdx.x & 63;
    int q = lane >> 4;
    int c4 = (lane & 15) << 2;
    float dd = dinv[node];
    int cnt = deg[node];
    int start = rowp[node];
    float4 acc = make_float4(0.f, 0.f, 0.f, 0.f);
    if (q == 0) {
        float4 xs = ldtab(tab, node, c4);
        float dd2 = dd * dd;
        acc.x = xs.x * dd2; acc.y = xs.y * dd2; acc.z = xs.z * dd2; acc.w = xs.w * dd2;
    }
    int j = 0;
    for (; j + 16 <= cnt; j += 16) {          // 16 edges in flight per wave
        int s[4]; float nv[4];
#pragma unroll
        for (int u = 0; u < 4; ++u) {
            int idx = start + j + 4 * u + q;
            if (USE_PCK) {
                unsigned p = pck[idx];
                s[u] = (int)(p & 0xFFFFu);
                nv[u] = unpack_n(p);
            } else {
                s[u] = col[idx];
                nv[u] = dinv[s[u]] * dd;
                if (WRITE_PCK && (lane & 15) == 0) pck[idx] = pack_sn(s[u], nv[u]);
            }
        }
#pragma unroll
        for (int u = 0; u < 4; ++u) {
            float4 xv = ldtab(tab, s[u], c4);
            acc.x = fmaf(nv[u], xv.x, acc.x); acc.y = fmaf(nv[u], xv.y, acc.y);
            acc.z = fmaf(nv[u], xv.z, acc.z); acc.w = fmaf(nv[u], xv.w, acc.w);
        }
    }
    for (; j + 8 <= cnt; j += 8) {
        int s[2]; float nv[2];
#pragma unroll
        for (int u = 0; u < 2; ++u) {
            int idx = start + j + 4 * u + q;
            if (USE_PCK) {
                unsigned p = pck[idx];
                s[u] = (int)(p & 0xFFFFu);
                nv[u] = unpack_n(p);
            } else {
                s[u] = col[idx];
                nv[u] = dinv[s[u]] * dd;
                if (WRITE_PCK && (lane & 15) == 0) pck[idx] = pack_sn(s[u], nv[u]);
            }
        }
#pragma unroll
        for (int u = 0; u < 2; ++u) {
            float4 xv = ldtab(tab, s[u], c4);
            acc.x = fmaf(nv[u], xv.x, acc.x); acc.y = fmaf(nv[u], xv.y, acc.y);
            acc.z = fmaf(nv[u], xv.z, acc.z); acc.w = fmaf(nv[u], xv.w, acc.w);
        }
    }
    for (; j < cnt; j += 4) {                 // predicated tail
        int jj = j + q;
        bool valid = jj < cnt;
        int s; float nv;
        if (USE_PCK) {
            unsigned p = pck[start + (valid ? jj : 0)];
            s = (int)(p & 0xFFFFu);
            nv = valid ? unpack_n(p) : 0.0f;
        } else {
            s = col[start + (valid ? jj : 0)];
            nv = valid ? dinv[s] * dd : 0.0f;
            if (WRITE_PCK && valid && (lane & 15) == 0) pck[start + jj] = pack_sn(s, nv);
        }
        float4 xv = ldtab(tab, s, c4);
        acc.x = fmaf(nv, xv.x, acc.x); acc.y = fmaf(nv, xv.y, acc.y);
        acc.z = fmaf(nv, xv.z, acc.z); acc.w = fmaf(nv, xv.w, acc.w);
    }
    acc.x += __shfl_xor(acc.x, 16); acc.y += __shfl_xor(acc.y, 16);
    acc.z += __shfl_xor(acc.z, 16); acc.w += __shfl_xor(acc.w, 16);
    acc.x += __shfl_xor(acc.x, 32); acc.y += __shfl_xor(acc.y, 32);
    acc.z += __shfl_xor(acc.z, 32); acc.w += __shfl_xor(acc.w, 32);
    if (q == 0) {
        if (bias) {
            float4 bv = *(const float4*)&bias[c4];
            acc.x += bv.x; acc.y += bv.y; acc.z += bv.z; acc.w += bv.w;
        }
        if (do_relu) {
            acc.x = fmaxf(acc.x, 0.f); acc.y = fmaxf(acc.y, 0.f);
            acc.z = fmaxf(acc.z, 0.f); acc.w = fmaxf(acc.w, 0.f);
        }
        if (OUT_BF16) {
            uint2 o;
            o.x = bf16_rne(acc.x) | (bf16_rne(acc.y) << 16);
            o.y = bf16_rne(acc.z) | (bf16_rne(acc.w) << 16);
            *(uint2*)&((unsigned short*)outv)[((size_t)node << 6) + c4] = o;
        } else {
            *(float4*)&((float*)outv)[((size_t)node << 6) + c4] = acc;
        }
    }
}

// ---------------- pool over bf16 Z (+ per-graph node count): batch sorted ----------------
__global__ void pool_seg(const unsigned short* __restrict__ h, const int* __restrict__ batch,
                         float* __restrict__ pool, float* __restrict__ cntg) {
    int ch = threadIdx.x & 63;
    int grp = threadIdx.x >> 6;
    int base = (blockIdx.x * 4 + grp) * 16;
    float acc = 0.0f;
    int curg = -1, runlen = 0;
    for (int n = 0; n < 16; ++n) {
        int node = base + n;
        if (node >= N_NODES) break;
        int g = batch[node];
        float v = __uint_as_float(((unsigned)h[((size_t)node << 6) + ch]) << 16);
        if (g != curg) {
            if (curg >= 0) {
                atomicAdd(&pool[curg * 64 + ch], acc);
                if (ch == 0) atomicAdd(&cntg[curg], (float)runlen);
            }
            curg = g; acc = v; runlen = 1;
        } else { acc += v; runlen++; }
    }
    if (curg >= 0) {
        atomicAdd(&pool[curg * 64 + ch], acc);
        if (ch == 0) atomicAdd(&cntg[curg], (float)runlen);
    }
}

// ---------------- tiny output GEMM: out = P @ W3 + cnt_g * b3 ----------------
__global__ void out_gemm(const float* __restrict__ P, const float* __restrict__ cntg,
                         const float* __restrict__ W, const float* __restrict__ b,
                         float* __restrict__ out) {
    __shared__ float Ws[64 * 64];
    int tid = threadIdx.x;
    for (int i = tid; i < 64 * 64; i += 256) Ws[i] = W[i];
    __syncthreads();
    int lane = tid & 63;
    int g = blockIdx.x * 4 + (tid >> 6);
    if (g >= N_GRAPHS) return;
    float pv = P[g * 64 + lane];
    float acc = 0.0f;
#pragma unroll
    for (int k = 0; k < 64; ++k)
        acc = fmaf(__shfl(pv, k, 64), Ws[k * 64 + lane], acc);
    out[g * 64 + lane] = acc + cntg[g] * b[lane];
}

extern "C" void kernel_launch(void* const* d_in, const int* in_sizes, int n_in,
                              void* d_out, int out_size, void* d_ws, size_t ws_size,
                              hipStream_t stream) {
    const float* x   = (const float*)d_in[0];
    const int* ei    = (const int*)d_in[1];   // int32 [2, N_EDGES]
    const int* batch = (const int*)d_in[2];   // int32 [N_NODES]
    const float* W1  = (const float*)d_in[3];
    const float* b1  = (const float*)d_in[4];
    const float* W2  = (const float*)d_in[5];
    const float* b2  = (const float*)d_in[6];
    const float* W3  = (const float*)d_in[7];
    const float* b3  = (const float*)d_in[8];
    float* out = (float*)d_out;

    // workspace layout (bytes), total ~32.8MB
    char* ws = (char*)d_ws;
    float*    dinv  = (float*)(ws);                 // 50000 f32
    int*      DEG   = (int*)(ws + 200192);          // 50048 i32
    int*      ROWP  = (int*)(ws + 400384);          // 50000 i32
    int*      COL   = (int*)(ws + 600576);          // 800000 i32
    unsigned* PCK   = (unsigned*)(ws + 3800576);    // 800000 u32 (src|f16norm)
    int*      HPART = (int*)(ws + 7000576);         // 98*196 i32 partial hists
    int*      BST   = (int*)(ws + 7077888);         // 197 i32
    int*      GCUR  = (int*)(ws + 7078912);         // 196 i32
    float*    XW    = (float*)(ws + 7080960);       // 12.8MB; first 3.2MB doubles as EBUF
    unsigned* EBUF  = (unsigned*)(ws + 7080960);    // 800000 u32 (dead after csr_bucket)
    float*    ACC   = (float*)(ws + 19880960);      // 12.8MB (bf16 H1/H2 in low half)
    float*    POOL  = (float*)(ws + 32680960);      // 16384 f32
    float*    CNT   = (float*)(ws + 32746496);      // 256 f32 (contiguous after POOL)

    const int WAVE_NODE_BLK = N_NODES / 4;          // 12500 (exact)
    const int GEMM_BLK = (N_NODES + 31) / 32;       // 1563
    const int SCAT_BLK = (N_EDGES + CHUNK - 1) / CHUNK;   // 391

    // ---- CSR build via 2-level counting sort (line-dense writes)
    edge_hist<<<NHIST, 256, 0, stream>>>(ei, HPART);
    bucket_scan<<<65, 256, 0, stream>>>(HPART, BST, GCUR, POOL);
    bin_scatter<<<SCAT_BLK, 256, 0, stream>>>(ei, GCUR, EBUF);
    csr_bucket<<<NBUCK, 256, 0, stream>>>(EBUF, BST, DEG, ROWP, dinv, COL);

    // ---- layer 1: x(f32) -> XW(bf16) -> H1(bf16) in ACC; writes packed src|norm stream
    gemm_reg<0><<<GEMM_BLK, 256, 0, stream>>>(x, W1, (unsigned short*)XW, N_NODES);
    agg_v4<1, 0, 1><<<WAVE_NODE_BLK, 256, 0, stream>>>(ROWP, DEG, COL, dinv, PCK,
        (const unsigned short*)XW, b1, ACC, 1);

    // ---- layer 2: H1(bf16) -> XW(bf16) -> H2(bf16) in ACC; streams packed edges
    gemm_reg<1><<<GEMM_BLK, 256, 0, stream>>>(ACC, W2, (unsigned short*)XW, N_NODES);
    agg_v4<1, 1, 0><<<WAVE_NODE_BLK, 256, 0, stream>>>(ROWP, DEG, COL, dinv, PCK,
        (const unsigned short*)XW, b2, ACC, 1);

    // ---- layer 3 (reordered): Z = A_hat H2 -> bf16 in XW -> pool -> small GEMM
    agg_v4<1, 1, 0><<<WAVE_NODE_BLK, 256, 0, stream>>>(ROWP, DEG, COL, dinv, PCK,
        (const unsigned short*)ACC, nullptr, XW, 0);
    pool_seg<<<(N_NODES + 63) / 64, 256, 0, stream>>>((const unsigned short*)XW,
        batch, POOL, CNT);
    out_gemm<<<N_GRAPHS / 4, 256, 0, stream>>>(POOL, CNT, W3, b3, out);
}

// Round 13
// 231.440 us; speedup vs baseline: 1.0556x; 1.0556x over previous
//
#include <hip/hip_runtime.h>
#include <hip/hip_bf16.h>
#include <hip/hip_fp16.h>

#define N_NODES 50000
#define N_EDGES 800000
#define CH 64
#define N_GRAPHS 256
#define NBUCK 196            // ceil(50000/256); bucket = dst >> 8
#define MAXB 4608            // padded bucket capacity (mean 4096, sigma~64)
#define NPAD (NBUCK * MAXB)  // 903168 padded edge slots
#define CHUNK 2048           // edges staged per scatter block
#define SCAT_BLK ((N_EDGES + CHUNK - 1) / CHUNK)   // 391
#define GEMM_BLK ((N_NODES + 31) / 32)             // 1563

__device__ __forceinline__ unsigned bf16_rne(float f) {
    unsigned u = __float_as_uint(f);
    return (u + 0x7fffu + ((u >> 16) & 1u)) >> 16;
}
__device__ __forceinline__ float4 ldtab(const unsigned short* __restrict__ tab, int s, int c4) {
    uint2 u = *(const uint2*)(tab + ((size_t)s << 6) + c4);
    float4 r;
    r.x = __uint_as_float(u.x << 16);
    r.y = __uint_as_float(u.x & 0xffff0000u);
    r.z = __uint_as_float(u.y << 16);
    r.w = __uint_as_float(u.y & 0xffff0000u);
    return r;
}
__device__ __forceinline__ unsigned pack_sn(int s, float n) {
    return (unsigned)s | ((unsigned)__half_as_ushort(__float2half_rn(n)) << 16);
}
__device__ __forceinline__ float unpack_n(unsigned p) {
    return __half2float(__ushort_as_half((unsigned short)(p >> 16)));
}

// ---------------- init: seed bucket cursors + zero POOL/CNT ----------------
__global__ void init_k(int* __restrict__ gcur, float* __restrict__ poolz) {
    int i = blockIdx.x * 256 + threadIdx.x;
    if (i < N_GRAPHS * CH + N_GRAPHS) poolz[i] = 0.0f;
    if (i < NBUCK) gcur[i] = i * MAXB;
}

// ---------------- fused: bin_scatter (blocks 0..390) || gemm1 (blocks 391..1953) ----------
union FusedSh {
    struct { float WT[64 * 68]; } g;                             // 17408 B
    struct {
        int hist[NBUCK]; int lofs[NBUCK]; int gbase[NBUCK]; int cur[NBUCK];
        int sc[256]; unsigned stage[CHUNK];
    } s;                                                         // 12352 B
};
__global__ __launch_bounds__(256) void gemm1_scatter(
        const float* __restrict__ x, const float* __restrict__ W1,
        unsigned short* __restrict__ xwout,
        const int* __restrict__ ei, int* __restrict__ gcur, unsigned* __restrict__ ebuf) {
    __shared__ FusedSh sh;
    int tid = threadIdx.x;
    if (blockIdx.x < SCAT_BLK) {
        // ---- scatter path ----
        for (int i = tid; i < NBUCK; i += 256) sh.s.hist[i] = 0;
        __syncthreads();
        int e0 = blockIdx.x * CHUNK;
        int n = min(CHUNK, N_EDGES - e0);
        int src[8], dst[8];
#pragma unroll
        for (int k = 0; k < 8; ++k) {
            int idx = k * 256 + tid;
            if (idx < n) {
                int e = e0 + idx;
                src[k] = ei[e];
                dst[k] = ei[N_EDGES + e];
                atomicAdd(&sh.s.hist[dst[k] >> 8], 1);
            } else dst[k] = -1;
        }
        __syncthreads();
        int v = (tid < NBUCK) ? sh.s.hist[tid] : 0;
        sh.s.sc[tid] = v;
        __syncthreads();
        for (int off = 1; off < 256; off <<= 1) {
            int t = (tid >= off) ? sh.s.sc[tid - off] : 0;
            __syncthreads();
            sh.s.sc[tid] += t;
            __syncthreads();
        }
        if (tid < NBUCK) {
            int ex = sh.s.sc[tid] - v;
            sh.s.lofs[tid] = ex;
            sh.s.cur[tid] = ex;
            sh.s.gbase[tid] = v ? atomicAdd(&gcur[tid], v) : 0;
        }
        __syncthreads();
#pragma unroll
        for (int k = 0; k < 8; ++k) {
            if (dst[k] >= 0) {
                int b = dst[k] >> 8;
                int p = atomicAdd(&sh.s.cur[b], 1);
                sh.s.stage[p] = (unsigned)src[k] | ((unsigned)(dst[k] & 255) << 16)
                                                | ((unsigned)b << 24);
            }
        }
        __syncthreads();
        for (int i = tid; i < n; i += 256) {
            unsigned p = sh.s.stage[i];
            int b = p >> 24;
            ebuf[sh.s.gbase[b] + (i - sh.s.lofs[b])] = p;   // contiguous per bucket
        }
    } else {
        // ---- gemm path (f32 input) ----
        for (int i = tid; i < 64 * 64; i += 256) {
            int k = i >> 6, c = i & 63;
            sh.g.WT[c * 68 + k] = W1[i];
        }
        __syncthreads();
        int lane = tid & 63;
        int wv = __builtin_amdgcn_readfirstlane(tid >> 6);
        int row0 = (blockIdx.x - SCAT_BLK) * 32 + wv * 8;
        if (row0 >= N_NODES) return;
        float acc[8] = {0.f, 0.f, 0.f, 0.f, 0.f, 0.f, 0.f, 0.f};
#pragma unroll 2
        for (int k = 0; k < 64; k += 4) {
            float4 w = *(const float4*)&sh.g.WT[lane * 68 + k];
#pragma unroll
            for (int r = 0; r < 8; ++r) {
                float4 xv = *(const float4*)&x[(size_t)(row0 + r) * 64 + k];  // scalar load
                acc[r] = fmaf(xv.x, w.x, acc[r]);
                acc[r] = fmaf(xv.y, w.y, acc[r]);
                acc[r] = fmaf(xv.z, w.z, acc[r]);
                acc[r] = fmaf(xv.w, w.w, acc[r]);
            }
        }
#pragma unroll
        for (int r = 0; r < 8; ++r)
            xwout[(size_t)(row0 + r) * 64 + lane] = (unsigned short)bf16_rne(acc[r]);
    }
}

// ---------------- per-bucket CSR build (deg, rowp, dinv, col; padded windows) -------------
__global__ void csr_bucket(const unsigned* __restrict__ ebuf, const int* __restrict__ gcur,
                           int* __restrict__ deg, int* __restrict__ rowp,
                           float* __restrict__ dinv, int* __restrict__ col) {
    __shared__ int nd[256];
    __shared__ int cur[256];
    __shared__ int sc[256];
    int b = blockIdx.x;
    int tid = threadIdx.x;
    nd[tid] = 0;
    __syncthreads();
    int es = b * MAXB, ee = gcur[b];
    for (int e = es + tid; e < ee; e += 256)
        atomicAdd(&nd[(ebuf[e] >> 16) & 255], 1);
    __syncthreads();
    int v = nd[tid];
    sc[tid] = v;
    __syncthreads();
    for (int off = 1; off < 256; off <<= 1) {
        int t = (tid >= off) ? sc[tid - off] : 0;
        __syncthreads();
        sc[tid] += t;
        __syncthreads();
    }
    int node = b * 256 + tid;
    int lstart = es + sc[tid] - v;
    if (node < N_NODES) {
        deg[node] = v;
        rowp[node] = lstart;
        dinv[node] = rsqrtf((float)v + 1.0f);
    }
    cur[tid] = lstart;
    __syncthreads();
    for (int e = es + tid; e < ee; e += 256) {
        unsigned p = ebuf[e];
        int pos = atomicAdd(&cur[(p >> 16) & 255], 1);
        col[pos] = (int)(p & 0xFFFFu);
    }
}

// ---------------- register-blocked GEMM -> bf16 out (bf16 input) ----------------
__global__ void gemm_reg_bf16(const unsigned short* __restrict__ in,
                              const float* __restrict__ W,
                              unsigned short* __restrict__ out, int n) {
    __shared__ float WT[64 * 68];
    int tid = threadIdx.x;
    for (int i = tid; i < 64 * 64; i += 256) {
        int k = i >> 6, c = i & 63;
        WT[c * 68 + k] = W[i];
    }
    __syncthreads();
    int lane = tid & 63;
    int wv = __builtin_amdgcn_readfirstlane(tid >> 6);
    int row0 = blockIdx.x * 32 + wv * 8;
    if (row0 >= n) return;
    float acc[8] = {0.f, 0.f, 0.f, 0.f, 0.f, 0.f, 0.f, 0.f};
#pragma unroll 2
    for (int k = 0; k < 64; k += 8) {
        float4 w0 = *(const float4*)&WT[lane * 68 + k];
        float4 w1 = *(const float4*)&WT[lane * 68 + k + 4];
#pragma unroll
        for (int r = 0; r < 8; ++r) {
            uint4 xb = *(const uint4*)&in[(size_t)(row0 + r) * 64 + k]; // scalar 16B = 8 bf16
            acc[r] = fmaf(__uint_as_float(xb.x << 16),         w0.x, acc[r]);
            acc[r] = fmaf(__uint_as_float(xb.x & 0xffff0000u), w0.y, acc[r]);
            acc[r] = fmaf(__uint_as_float(xb.y << 16),         w0.z, acc[r]);
            acc[r] = fmaf(__uint_as_float(xb.y & 0xffff0000u), w0.w, acc[r]);
            acc[r] = fmaf(__uint_as_float(xb.z << 16),         w1.x, acc[r]);
            acc[r] = fmaf(__uint_as_float(xb.z & 0xffff0000u), w1.y, acc[r]);
            acc[r] = fmaf(__uint_as_float(xb.w << 16),         w1.z, acc[r]);
            acc[r] = fmaf(__uint_as_float(xb.w & 0xffff0000u), w1.w, acc[r]);
        }
    }
#pragma unroll
    for (int r = 0; r < 8; ++r)
        out[(size_t)(row0 + r) * 64 + lane] = (unsigned short)bf16_rne(acc[r]);
}

// ---------------- fused aggregation, float4-quad form, 16 edges in flight ----------------
template <int USE_PCK, int WRITE_PCK>
__global__ void agg_v4(const int* __restrict__ rowp, const int* __restrict__ deg,
                       const int* __restrict__ col, const float* __restrict__ dinv,
                       unsigned* __restrict__ pck,
                       const unsigned short* __restrict__ tab, const float* __restrict__ bias,
                       unsigned short* __restrict__ outv, int do_relu) {
    int wv = __builtin_amdgcn_readfirstlane(threadIdx.x >> 6);
    int node = blockIdx.x * 4 + wv;
    int lane = threadIdx.x & 63;
    int q = lane >> 4;
    int c4 = (lane & 15) << 2;
    float dd = dinv[node];
    int cnt = deg[node];
    int start = rowp[node];
    float4 acc = make_float4(0.f, 0.f, 0.f, 0.f);
    if (q == 0) {
        float4 xs = ldtab(tab, node, c4);
        float dd2 = dd * dd;
        acc.x = xs.x * dd2; acc.y = xs.y * dd2; acc.z = xs.z * dd2; acc.w = xs.w * dd2;
    }
    int j = 0;
    for (; j + 16 <= cnt; j += 16) {
        int s[4]; float nv[4];
#pragma unroll
        for (int u = 0; u < 4; ++u) {
            int idx = start + j + 4 * u + q;
            if (USE_PCK) {
                unsigned p = pck[idx];
                s[u] = (int)(p & 0xFFFFu);
                nv[u] = unpack_n(p);
            } else {
                s[u] = col[idx];
                nv[u] = dinv[s[u]] * dd;
                if (WRITE_PCK && (lane & 15) == 0) pck[idx] = pack_sn(s[u], nv[u]);
            }
        }
#pragma unroll
        for (int u = 0; u < 4; ++u) {
            float4 xv = ldtab(tab, s[u], c4);
            acc.x = fmaf(nv[u], xv.x, acc.x); acc.y = fmaf(nv[u], xv.y, acc.y);
            acc.z = fmaf(nv[u], xv.z, acc.z); acc.w = fmaf(nv[u], xv.w, acc.w);
        }
    }
    for (; j + 8 <= cnt; j += 8) {
        int s[2]; float nv[2];
#pragma unroll
        for (int u = 0; u < 2; ++u) {
            int idx = start + j + 4 * u + q;
            if (USE_PCK) {
                unsigned p = pck[idx];
                s[u] = (int)(p & 0xFFFFu);
                nv[u] = unpack_n(p);
            } else {
                s[u] = col[idx];
                nv[u] = dinv[s[u]] * dd;
                if (WRITE_PCK && (lane & 15) == 0) pck[idx] = pack_sn(s[u], nv[u]);
            }
        }
#pragma unroll
        for (int u = 0; u < 2; ++u) {
            float4 xv = ldtab(tab, s[u], c4);
            acc.x = fmaf(nv[u], xv.x, acc.x); acc.y = fmaf(nv[u], xv.y, acc.y);
            acc.z = fmaf(nv[u], xv.z, acc.z); acc.w = fmaf(nv[u], xv.w, acc.w);
        }
    }
    for (; j < cnt; j += 4) {
        int jj = j + q;
        bool valid = jj < cnt;
        int s; float nv;
        if (USE_PCK) {
            unsigned p = pck[start + (valid ? jj : 0)];
            s = (int)(p & 0xFFFFu);
            nv = valid ? unpack_n(p) : 0.0f;
        } else {
            s = col[start + (valid ? jj : 0)];
            nv = valid ? dinv[s] * dd : 0.0f;
            if (WRITE_PCK && valid && (lane & 15) == 0) pck[start + jj] = pack_sn(s, nv);
        }
        float4 xv = ldtab(tab, s, c4);
        acc.x = fmaf(nv, xv.x, acc.x); acc.y = fmaf(nv, xv.y, acc.y);
        acc.z = fmaf(nv, xv.z, acc.z); acc.w = fmaf(nv, xv.w, acc.w);
    }
    acc.x += __shfl_xor(acc.x, 16); acc.y += __shfl_xor(acc.y, 16);
    acc.z += __shfl_xor(acc.z, 16); acc.w += __shfl_xor(acc.w, 16);
    acc.x += __shfl_xor(acc.x, 32); acc.y += __shfl_xor(acc.y, 32);
    acc.z += __shfl_xor(acc.z, 32); acc.w += __shfl_xor(acc.w, 32);
    if (q == 0) {
        if (bias) {
            float4 bv = *(const float4*)&bias[c4];
            acc.x += bv.x; acc.y += bv.y; acc.z += bv.z; acc.w += bv.w;
        }
        if (do_relu) {
            acc.x = fmaxf(acc.x, 0.f); acc.y = fmaxf(acc.y, 0.f);
            acc.z = fmaxf(acc.z, 0.f); acc.w = fmaxf(acc.w, 0.f);
        }
        uint2 o;
        o.x = bf16_rne(acc.x) | (bf16_rne(acc.y) << 16);
        o.y = bf16_rne(acc.z) | (bf16_rne(acc.w) << 16);
        *(uint2*)&outv[((size_t)node << 6) + c4] = o;
    }
}

// ---------------- pool over bf16 Z (+ per-graph node count): batch sorted ----------------
__global__ void pool_seg(const unsigned short* __restrict__ h, const int* __restrict__ batch,
                         float* __restrict__ pool, float* __restrict__ cntg) {
    int ch = threadIdx.x & 63;
    int grp = threadIdx.x >> 6;
    int base = (blockIdx.x * 4 + grp) * 16;
    float acc = 0.0f;
    int curg = -1, runlen = 0;
    for (int n = 0; n < 16; ++n) {
        int node = base + n;
        if (node >= N_NODES) break;
        int g = batch[node];
        float v = __uint_as_float(((unsigned)h[((size_t)node << 6) + ch]) << 16);
        if (g != curg) {
            if (curg >= 0) {
                atomicAdd(&pool[curg * 64 + ch], acc);
                if (ch == 0) atomicAdd(&cntg[curg], (float)runlen);
            }
            curg = g; acc = v; runlen = 1;
        } else { acc += v; runlen++; }
    }
    if (curg >= 0) {
        atomicAdd(&pool[curg * 64 + ch], acc);
        if (ch == 0) atomicAdd(&cntg[curg], (float)runlen);
    }
}

// ---------------- tiny output GEMM: out = P @ W3 + cnt_g * b3 ----------------
__global__ void out_gemm(const float* __restrict__ P, const float* __restrict__ cntg,
                         const float* __restrict__ W, const float* __restrict__ b,
                         float* __restrict__ out) {
    __shared__ float Ws[64 * 64];
    int tid = threadIdx.x;
    for (int i = tid; i < 64 * 64; i += 256) Ws[i] = W[i];
    __syncthreads();
    int lane = tid & 63;
    int g = blockIdx.x * 4 + (tid >> 6);
    if (g >= N_GRAPHS) return;
    float pv = P[g * 64 + lane];
    float acc = 0.0f;
#pragma unroll
    for (int k = 0; k < 64; ++k)
        acc = fmaf(__shfl(pv, k, 64), Ws[k * 64 + lane], acc);
    out[g * 64 + lane] = acc + cntg[g] * b[lane];
}

extern "C" void kernel_launch(void* const* d_in, const int* in_sizes, int n_in,
                              void* d_out, int out_size, void* d_ws, size_t ws_size,
                              hipStream_t stream) {
    const float* x   = (const float*)d_in[0];
    const int* ei    = (const int*)d_in[1];   // int32 [2, N_EDGES]
    const int* batch = (const int*)d_in[2];   // int32 [N_NODES]
    const float* W1  = (const float*)d_in[3];
    const float* b1  = (const float*)d_in[4];
    const float* W2  = (const float*)d_in[5];
    const float* b2  = (const float*)d_in[6];
    const float* W3  = (const float*)d_in[7];
    const float* b3  = (const float*)d_in[8];
    float* out = (float*)d_out;

    // workspace layout (bytes), total ~37.1MB; PCK/COL/EBUF sized for the
    // PADDED index space NPAD=903168 (round-12 bug: PCK at 800000 overflowed into XW)
    char* ws = (char*)d_ws;
    float*    dinv = (float*)(ws);                   // 50048 f32   -> ends   200192
    int*      DEG  = (int*)(ws + 200192);            // 50048 i32   -> ends   400384
    int*      ROWP = (int*)(ws + 400384);            // 50048 i32   -> ends   600576
    int*      COL  = (int*)(ws + 600576);            // NPAD i32    -> ends  4213248
    unsigned* PCK  = (unsigned*)(ws + 4213248);      // NPAD u32    -> ends  7825920
    float*    XW   = (float*)(ws + 7825920);         // 12.8MB      -> ends 20625920
    float*    ACC  = (float*)(ws + 20625920);        // 12.8MB      -> ends 33425920
    float*    POOL = (float*)(ws + 33425920);        // 16384 f32   -> ends 33491456
    float*    CNT  = (float*)(ws + 33491456);        // 256 f32 (contiguous after POOL)
    int*      GCUR = (int*)(ws + 33492480);          // 196 i32
    unsigned* EBUF = (unsigned*)(ws + 33493504);     // NPAD u32    -> ends 37106176

    const int WAVE_NODE_BLK = N_NODES / 4;           // 12500 (exact)

    // ---- init cursors + POOL zero
    init_k<<<66, 256, 0, stream>>>(GCUR, POOL);

    // ---- fused: edge bin-scatter (391 blks) || gemm1 x@W1->XW bf16 (1563 blks)
    gemm1_scatter<<<SCAT_BLK + GEMM_BLK, 256, 0, stream>>>(
        x, W1, (unsigned short*)XW, ei, GCUR, EBUF);

    // ---- per-bucket CSR finalize
    csr_bucket<<<NBUCK, 256, 0, stream>>>(EBUF, GCUR, DEG, ROWP, dinv, COL);

    // ---- layer 1 agg: XW -> H1(bf16) in ACC; writes packed src|f16norm stream
    agg_v4<0, 1><<<WAVE_NODE_BLK, 256, 0, stream>>>(ROWP, DEG, COL, dinv, PCK,
        (const unsigned short*)XW, b1, (unsigned short*)ACC, 1);

    // ---- layer 2: H1(bf16) -> XW(bf16); agg -> H2(bf16) in ACC
    gemm_reg_bf16<<<GEMM_BLK, 256, 0, stream>>>((const unsigned short*)ACC, W2,
        (unsigned short*)XW, N_NODES);
    agg_v4<1, 0><<<WAVE_NODE_BLK, 256, 0, stream>>>(ROWP, DEG, COL, dinv, PCK,
        (const unsigned short*)XW, b2, (unsigned short*)ACC, 1);

    // ---- layer 3 (reordered): Z = A_hat H2 -> bf16 in XW -> pool -> small GEMM
    agg_v4<1, 0><<<WAVE_NODE_BLK, 256, 0, stream>>>(ROWP, DEG, COL, dinv, PCK,
        (const unsigned short*)ACC, nullptr, (unsigned short*)XW, 0);
    pool_seg<<<(N_NODES + 63) / 64, 256, 0, stream>>>((const unsigned short*)XW,
        batch, POOL, CNT);
    out_gemm<<<N_GRAPHS / 4, 256, 0, stream>>>(POOL, CNT, W3, b3, out);
}

// Round 14
// 227.028 us; speedup vs baseline: 1.0761x; 1.0194x over previous
//
#include <hip/hip_runtime.h>
#include <hip/hip_bf16.h>
#include <hip/hip_fp16.h>

#define N_NODES 50000
#define N_EDGES 800000
#define CH 64
#define N_GRAPHS 256
#define NBUCK 196            // ceil(50000/256); bucket = dst >> 8
#define MAXB 4608            // padded bucket capacity (mean 4096, sigma~64)
#define NPAD (NBUCK * MAXB)  // 903168 padded edge slots
#define CHUNK 2048           // edges staged per scatter block
#define SCAT_BLK ((N_EDGES + CHUNK - 1) / CHUNK)   // 391
#define GEMM_BLK ((N_NODES + 31) / 32)             // 1563

__device__ __forceinline__ unsigned bf16_rne(float f) {
    unsigned u = __float_as_uint(f);
    return (u + 0x7fffu + ((u >> 16) & 1u)) >> 16;
}
__device__ __forceinline__ float4 ldtab(const unsigned short* __restrict__ tab, int s, int c4) {
    uint2 u = *(const uint2*)(tab + ((size_t)s << 6) + c4);
    float4 r;
    r.x = __uint_as_float(u.x << 16);
    r.y = __uint_as_float(u.x & 0xffff0000u);
    r.z = __uint_as_float(u.y << 16);
    r.w = __uint_as_float(u.y & 0xffff0000u);
    return r;
}
__device__ __forceinline__ unsigned pack_sn(int s, float n) {
    return (unsigned)s | ((unsigned)__half_as_ushort(__float2half_rn(n)) << 16);
}
__device__ __forceinline__ float unpack_n(unsigned p) {
    return __half2float(__ushort_as_half((unsigned short)(p >> 16)));
}

// ---------------- init: seed bucket cursors (1 block) ----------------
__global__ void init_k(int* __restrict__ gcur) {
    if (threadIdx.x < NBUCK) gcur[threadIdx.x] = threadIdx.x * MAXB;
}

// ---------------- fused: bin_scatter (blocks 0..390) || gemm1 (blocks 391..1953) ----------
union FusedSh {
    struct { float WT[64 * 68]; } g;                             // 17408 B
    struct {
        int hist[NBUCK]; int lofs[NBUCK]; int gbase[NBUCK]; int cur[NBUCK];
        int sc[256]; unsigned stage[CHUNK];
    } s;                                                         // 12352 B
};
__global__ __launch_bounds__(256) void gemm1_scatter(
        const float* __restrict__ x, const float* __restrict__ W1,
        unsigned short* __restrict__ xwout,
        const int* __restrict__ ei, int* __restrict__ gcur, unsigned* __restrict__ ebuf) {
    __shared__ FusedSh sh;
    int tid = threadIdx.x;
    if (blockIdx.x < SCAT_BLK) {
        // ---- scatter path ----
        for (int i = tid; i < NBUCK; i += 256) sh.s.hist[i] = 0;
        __syncthreads();
        int e0 = blockIdx.x * CHUNK;
        int n = min(CHUNK, N_EDGES - e0);
        int src[8], dst[8];
#pragma unroll
        for (int k = 0; k < 8; ++k) {
            int idx = k * 256 + tid;
            if (idx < n) {
                int e = e0 + idx;
                src[k] = ei[e];
                dst[k] = ei[N_EDGES + e];
                atomicAdd(&sh.s.hist[dst[k] >> 8], 1);
            } else dst[k] = -1;
        }
        __syncthreads();
        int v = (tid < NBUCK) ? sh.s.hist[tid] : 0;
        sh.s.sc[tid] = v;
        __syncthreads();
        for (int off = 1; off < 256; off <<= 1) {
            int t = (tid >= off) ? sh.s.sc[tid - off] : 0;
            __syncthreads();
            sh.s.sc[tid] += t;
            __syncthreads();
        }
        if (tid < NBUCK) {
            int ex = sh.s.sc[tid] - v;
            sh.s.lofs[tid] = ex;
            sh.s.cur[tid] = ex;
            sh.s.gbase[tid] = v ? atomicAdd(&gcur[tid], v) : 0;
        }
        __syncthreads();
#pragma unroll
        for (int k = 0; k < 8; ++k) {
            if (dst[k] >= 0) {
                int b = dst[k] >> 8;
                int p = atomicAdd(&sh.s.cur[b], 1);
                sh.s.stage[p] = (unsigned)src[k] | ((unsigned)(dst[k] & 255) << 16)
                                                | ((unsigned)b << 24);
            }
        }
        __syncthreads();
        for (int i = tid; i < n; i += 256) {
            unsigned p = sh.s.stage[i];
            int b = p >> 24;
            ebuf[sh.s.gbase[b] + (i - sh.s.lofs[b])] = p;   // contiguous per bucket
        }
    } else {
        // ---- gemm path (f32 input) ----
        for (int i = tid; i < 64 * 64; i += 256) {
            int k = i >> 6, c = i & 63;
            sh.g.WT[c * 68 + k] = W1[i];
        }
        __syncthreads();
        int lane = tid & 63;
        int wv = __builtin_amdgcn_readfirstlane(tid >> 6);
        int row0 = (blockIdx.x - SCAT_BLK) * 32 + wv * 8;
        if (row0 >= N_NODES) return;
        float acc[8] = {0.f, 0.f, 0.f, 0.f, 0.f, 0.f, 0.f, 0.f};
#pragma unroll 2
        for (int k = 0; k < 64; k += 4) {
            float4 w = *(const float4*)&sh.g.WT[lane * 68 + k];
#pragma unroll
            for (int r = 0; r < 8; ++r) {
                float4 xv = *(const float4*)&x[(size_t)(row0 + r) * 64 + k];  // scalar load
                acc[r] = fmaf(xv.x, w.x, acc[r]);
                acc[r] = fmaf(xv.y, w.y, acc[r]);
                acc[r] = fmaf(xv.z, w.z, acc[r]);
                acc[r] = fmaf(xv.w, w.w, acc[r]);
            }
        }
#pragma unroll
        for (int r = 0; r < 8; ++r)
            xwout[(size_t)(row0 + r) * 64 + lane] = (unsigned short)bf16_rne(acc[r]);
    }
}

// -------- per-bucket CSR build (deg, rowp, dinv, col) + POOL/CNT zero ----------
__global__ void csr_bucket(const unsigned* __restrict__ ebuf, const int* __restrict__ gcur,
                           int* __restrict__ deg, int* __restrict__ rowp,
                           float* __restrict__ dinv, int* __restrict__ col,
                           float* __restrict__ poolz) {
    __shared__ int nd[256];
    __shared__ int cur[256];
    __shared__ int sc[256];
    int b = blockIdx.x;
    int tid = threadIdx.x;
    // zero POOL+CNT slice (16640 floats over 196 blocks)
    {
        int zi = b * 85 + (tid % 85);
        if (tid < 85 && zi < N_GRAPHS * CH + N_GRAPHS) poolz[zi] = 0.0f;
    }
    nd[tid] = 0;
    __syncthreads();
    int es = b * MAXB, ee = gcur[b];
    for (int e = es + tid; e < ee; e += 256)
        atomicAdd(&nd[(ebuf[e] >> 16) & 255], 1);
    __syncthreads();
    int v = nd[tid];
    sc[tid] = v;
    __syncthreads();
    for (int off = 1; off < 256; off <<= 1) {
        int t = (tid >= off) ? sc[tid - off] : 0;
        __syncthreads();
        sc[tid] += t;
        __syncthreads();
    }
    int node = b * 256 + tid;
    int lstart = es + sc[tid] - v;
    if (node < N_NODES) {
        deg[node] = v;
        rowp[node] = lstart;
        dinv[node] = rsqrtf((float)v + 1.0f);
    }
    cur[tid] = lstart;
    __syncthreads();
    for (int e = es + tid; e < ee; e += 256) {
        unsigned p = ebuf[e];
        int pos = atomicAdd(&cur[(p >> 16) & 255], 1);
        col[pos] = (int)(p & 0xFFFFu);
    }
}

// ---- fused layer-1 agg + gemm2: H1 = relu(agg(XW1)+b1) kept in regs; writes XW2 = H1@W2 ----
__global__ void agg1_gemm2(const int* __restrict__ rowp, const int* __restrict__ deg,
                           const int* __restrict__ col, const float* __restrict__ dinv,
                           unsigned* __restrict__ pck,
                           const unsigned short* __restrict__ tab,
                           const float* __restrict__ b1, const float* __restrict__ W2,
                           unsigned short* __restrict__ xw2out) {
    __shared__ float Wsh[64 * 64];          // W2 row-major: Wsh[k*64+o]
    int tid = threadIdx.x;
    for (int i = tid; i < 64 * 64; i += 256) Wsh[i] = W2[i];
    __syncthreads();
    int wv = __builtin_amdgcn_readfirstlane(tid >> 6);
    int node = blockIdx.x * 4 + wv;
    int lane = tid & 63;
    int q = lane >> 4;
    int c4 = (lane & 15) << 2;
    float dd = dinv[node];
    int cnt = deg[node];
    int start = rowp[node];
    float4 acc = make_float4(0.f, 0.f, 0.f, 0.f);
    if (q == 0) {
        float4 xs = ldtab(tab, node, c4);
        float dd2 = dd * dd;
        acc.x = xs.x * dd2; acc.y = xs.y * dd2; acc.z = xs.z * dd2; acc.w = xs.w * dd2;
    }
    int j = 0;
    for (; j + 16 <= cnt; j += 16) {
        int s[4]; float nv[4];
#pragma unroll
        for (int u = 0; u < 4; ++u) {
            int idx = start + j + 4 * u + q;
            s[u] = col[idx];
            nv[u] = dinv[s[u]] * dd;
            if ((lane & 15) == 0) pck[idx] = pack_sn(s[u], nv[u]);
        }
#pragma unroll
        for (int u = 0; u < 4; ++u) {
            float4 xv = ldtab(tab, s[u], c4);
            acc.x = fmaf(nv[u], xv.x, acc.x); acc.y = fmaf(nv[u], xv.y, acc.y);
            acc.z = fmaf(nv[u], xv.z, acc.z); acc.w = fmaf(nv[u], xv.w, acc.w);
        }
    }
    for (; j + 8 <= cnt; j += 8) {
        int s[2]; float nv[2];
#pragma unroll
        for (int u = 0; u < 2; ++u) {
            int idx = start + j + 4 * u + q;
            s[u] = col[idx];
            nv[u] = dinv[s[u]] * dd;
            if ((lane & 15) == 0) pck[idx] = pack_sn(s[u], nv[u]);
        }
#pragma unroll
        for (int u = 0; u < 2; ++u) {
            float4 xv = ldtab(tab, s[u], c4);
            acc.x = fmaf(nv[u], xv.x, acc.x); acc.y = fmaf(nv[u], xv.y, acc.y);
            acc.z = fmaf(nv[u], xv.z, acc.z); acc.w = fmaf(nv[u], xv.w, acc.w);
        }
    }
    for (; j < cnt; j += 4) {
        int jj = j + q;
        bool valid = jj < cnt;
        int s = col[start + (valid ? jj : 0)];
        float nv = valid ? dinv[s] * dd : 0.0f;
        if (valid && (lane & 15) == 0) pck[start + jj] = pack_sn(s, nv);
        float4 xv = ldtab(tab, s, c4);
        acc.x = fmaf(nv, xv.x, acc.x); acc.y = fmaf(nv, xv.y, acc.y);
        acc.z = fmaf(nv, xv.z, acc.z); acc.w = fmaf(nv, xv.w, acc.w);
    }
    acc.x += __shfl_xor(acc.x, 16); acc.y += __shfl_xor(acc.y, 16);
    acc.z += __shfl_xor(acc.z, 16); acc.w += __shfl_xor(acc.w, 16);
    acc.x += __shfl_xor(acc.x, 32); acc.y += __shfl_xor(acc.y, 32);
    acc.z += __shfl_xor(acc.z, 32); acc.w += __shfl_xor(acc.w, 32);
    // all lanes: H1 quad (c4..c4+3) = relu(acc + b1)
    {
        float4 bv = *(const float4*)&b1[c4];
        acc.x = fmaxf(acc.x + bv.x, 0.f); acc.y = fmaxf(acc.y + bv.y, 0.f);
        acc.z = fmaxf(acc.z + bv.z, 0.f); acc.w = fmaxf(acc.w + bv.w, 0.f);
    }
    // epilogue GEMM: this lane accumulates out[c4..c4+3] over k in [16q, 16q+16)
    float hq[16];
#pragma unroll
    for (int t = 0; t < 4; ++t) {
        int sl = 4 * q + t;                      // lane holding H1 quad for k=4*sl..+3
        hq[4 * t + 0] = __shfl(acc.x, sl, 64);
        hq[4 * t + 1] = __shfl(acc.y, sl, 64);
        hq[4 * t + 2] = __shfl(acc.z, sl, 64);
        hq[4 * t + 3] = __shfl(acc.w, sl, 64);
    }
    float4 g = make_float4(0.f, 0.f, 0.f, 0.f);
#pragma unroll
    for (int kk = 0; kk < 16; ++kk) {
        int k = 16 * q + kk;
        float4 wv = *(const float4*)&Wsh[(k << 6) + c4];
        g.x = fmaf(hq[kk], wv.x, g.x); g.y = fmaf(hq[kk], wv.y, g.y);
        g.z = fmaf(hq[kk], wv.z, g.z); g.w = fmaf(hq[kk], wv.w, g.w);
    }
    g.x += __shfl_xor(g.x, 16); g.y += __shfl_xor(g.y, 16);
    g.z += __shfl_xor(g.z, 16); g.w += __shfl_xor(g.w, 16);
    g.x += __shfl_xor(g.x, 32); g.y += __shfl_xor(g.y, 32);
    g.z += __shfl_xor(g.z, 32); g.w += __shfl_xor(g.w, 32);
    if (q == 0) {
        uint2 o;
        o.x = bf16_rne(g.x) | (bf16_rne(g.y) << 16);
        o.y = bf16_rne(g.z) | (bf16_rne(g.w) << 16);
        *(uint2*)&xw2out[((size_t)node << 6) + c4] = o;
    }
}

// ---------------- plain aggregation (layers 2-3), packed-edge stream ----------------
__global__ void agg_v4(const int* __restrict__ rowp, const int* __restrict__ deg,
                       const float* __restrict__ dinv, const unsigned* __restrict__ pck,
                       const unsigned short* __restrict__ tab, const float* __restrict__ bias,
                       unsigned short* __restrict__ outv, int do_relu) {
    int wv = __builtin_amdgcn_readfirstlane(threadIdx.x >> 6);
    int node = blockIdx.x * 4 + wv;
    int lane = threadIdx.x & 63;
    int q = lane >> 4;
    int c4 = (lane & 15) << 2;
    float dd = dinv[node];
    int cnt = deg[node];
    int start = rowp[node];
    float4 acc = make_float4(0.f, 0.f, 0.f, 0.f);
    if (q == 0) {
        float4 xs = ldtab(tab, node, c4);
        float dd2 = dd * dd;
        acc.x = xs.x * dd2; acc.y = xs.y * dd2; acc.z = xs.z * dd2; acc.w = xs.w * dd2;
    }
    int j = 0;
    for (; j + 16 <= cnt; j += 16) {
        int s[4]; float nv[4];
#pragma unroll
        for (int u = 0; u < 4; ++u) {
            unsigned p = pck[start + j + 4 * u + q];
            s[u] = (int)(p & 0xFFFFu);
            nv[u] = unpack_n(p);
        }
#pragma unroll
        for (int u = 0; u < 4; ++u) {
            float4 xv = ldtab(tab, s[u], c4);
            acc.x = fmaf(nv[u], xv.x, acc.x); acc.y = fmaf(nv[u], xv.y, acc.y);
            acc.z = fmaf(nv[u], xv.z, acc.z); acc.w = fmaf(nv[u], xv.w, acc.w);
        }
    }
    for (; j + 8 <= cnt; j += 8) {
        int s[2]; float nv[2];
#pragma unroll
        for (int u = 0; u < 2; ++u) {
            unsigned p = pck[start + j + 4 * u + q];
            s[u] = (int)(p & 0xFFFFu);
            nv[u] = unpack_n(p);
        }
#pragma unroll
        for (int u = 0; u < 2; ++u) {
            float4 xv = ldtab(tab, s[u], c4);
            acc.x = fmaf(nv[u], xv.x, acc.x); acc.y = fmaf(nv[u], xv.y, acc.y);
            acc.z = fmaf(nv[u], xv.z, acc.z); acc.w = fmaf(nv[u], xv.w, acc.w);
        }
    }
    for (; j < cnt; j += 4) {
        int jj = j + q;
        bool valid = jj < cnt;
        unsigned p = pck[start + (valid ? jj : 0)];
        int s = (int)(p & 0xFFFFu);
        float nv = valid ? unpack_n(p) : 0.0f;
        float4 xv = ldtab(tab, s, c4);
        acc.x = fmaf(nv, xv.x, acc.x); acc.y = fmaf(nv, xv.y, acc.y);
        acc.z = fmaf(nv, xv.z, acc.z); acc.w = fmaf(nv, xv.w, acc.w);
    }
    acc.x += __shfl_xor(acc.x, 16); acc.y += __shfl_xor(acc.y, 16);
    acc.z += __shfl_xor(acc.z, 16); acc.w += __shfl_xor(acc.w, 16);
    acc.x += __shfl_xor(acc.x, 32); acc.y += __shfl_xor(acc.y, 32);
    acc.z += __shfl_xor(acc.z, 32); acc.w += __shfl_xor(acc.w, 32);
    if (q == 0) {
        if (bias) {
            float4 bv = *(const float4*)&bias[c4];
            acc.x += bv.x; acc.y += bv.y; acc.z += bv.z; acc.w += bv.w;
        }
        if (do_relu) {
            acc.x = fmaxf(acc.x, 0.f); acc.y = fmaxf(acc.y, 0.f);
            acc.z = fmaxf(acc.z, 0.f); acc.w = fmaxf(acc.w, 0.f);
        }
        uint2 o;
        o.x = bf16_rne(acc.x) | (bf16_rne(acc.y) << 16);
        o.y = bf16_rne(acc.z) | (bf16_rne(acc.w) << 16);
        *(uint2*)&outv[((size_t)node << 6) + c4] = o;
    }
}

// ---------------- pool over bf16 Z (+ per-graph node count): batch sorted ----------------
__global__ void pool_seg(const unsigned short* __restrict__ h, const int* __restrict__ batch,
                         float* __restrict__ pool, float* __restrict__ cntg) {
    int ch = threadIdx.x & 63;
    int grp = threadIdx.x >> 6;
    int base = (blockIdx.x * 4 + grp) * 16;
    float acc = 0.0f;
    int curg = -1, runlen = 0;
    for (int n = 0; n < 16; ++n) {
        int node = base + n;
        if (node >= N_NODES) break;
        int g = batch[node];
        float v = __uint_as_float(((unsigned)h[((size_t)node << 6) + ch]) << 16);
        if (g != curg) {
            if (curg >= 0) {
                atomicAdd(&pool[curg * 64 + ch], acc);
                if (ch == 0) atomicAdd(&cntg[curg], (float)runlen);
            }
            curg = g; acc = v; runlen = 1;
        } else { acc += v; runlen++; }
    }
    if (curg >= 0) {
        atomicAdd(&pool[curg * 64 + ch], acc);
        if (ch == 0) atomicAdd(&cntg[curg], (float)runlen);
    }
}

// ---------------- tiny output GEMM: out = P @ W3 + cnt_g * b3 ----------------
__global__ void out_gemm(const float* __restrict__ P, const float* __restrict__ cntg,
                         const float* __restrict__ W, const float* __restrict__ b,
                         float* __restrict__ out) {
    __shared__ float Ws[64 * 64];
    int tid = threadIdx.x;
    for (int i = tid; i < 64 * 64; i += 256) Ws[i] = W[i];
    __syncthreads();
    int lane = tid & 63;
    int g = blockIdx.x * 4 + (tid >> 6);
    if (g >= N_GRAPHS) return;
    float pv = P[g * 64 + lane];
    float acc = 0.0f;
#pragma unroll
    for (int k = 0; k < 64; ++k)
        acc = fmaf(__shfl(pv, k, 64), Ws[k * 64 + lane], acc);
    out[g * 64 + lane] = acc + cntg[g] * b[lane];
}

extern "C" void kernel_launch(void* const* d_in, const int* in_sizes, int n_in,
                              void* d_out, int out_size, void* d_ws, size_t ws_size,
                              hipStream_t stream) {
    const float* x   = (const float*)d_in[0];
    const int* ei    = (const int*)d_in[1];   // int32 [2, N_EDGES]
    const int* batch = (const int*)d_in[2];   // int32 [N_NODES]
    const float* W1  = (const float*)d_in[3];
    const float* b1  = (const float*)d_in[4];
    const float* W2  = (const float*)d_in[5];
    const float* b2  = (const float*)d_in[6];
    const float* W3  = (const float*)d_in[7];
    const float* b3  = (const float*)d_in[8];
    float* out = (float*)d_out;

    // workspace layout (bytes), total ~37.1MB; PCK/COL/EBUF sized for NPAD=903168
    char* ws = (char*)d_ws;
    float*    dinv = (float*)(ws);                   // 50048 f32   -> ends   200192
    int*      DEG  = (int*)(ws + 200192);            // 50048 i32   -> ends   400384
    int*      ROWP = (int*)(ws + 400384);            // 50048 i32   -> ends   600576
    int*      COL  = (int*)(ws + 600576);            // NPAD i32    -> ends  4213248
    unsigned* PCK  = (unsigned*)(ws + 4213248);      // NPAD u32    -> ends  7825920
    float*    XW   = (float*)(ws + 7825920);         // 12.8MB      -> ends 20625920
    float*    ACC  = (float*)(ws + 20625920);        // 12.8MB      -> ends 33425920
    float*    POOL = (float*)(ws + 33425920);        // 16384 f32   -> ends 33491456
    float*    CNT  = (float*)(ws + 33491456);        // 256 f32 (contiguous after POOL)
    int*      GCUR = (int*)(ws + 33492480);          // 196 i32
    unsigned* EBUF = (unsigned*)(ws + 33493504);     // NPAD u32    -> ends 37106176

    const int WAVE_NODE_BLK = N_NODES / 4;           // 12500 (exact)

    // ---- init bucket cursors
    init_k<<<1, 256, 0, stream>>>(GCUR);

    // ---- fused: edge bin-scatter (391 blks) || gemm1 x@W1->XW1 bf16 (1563 blks)
    gemm1_scatter<<<SCAT_BLK + GEMM_BLK, 256, 0, stream>>>(
        x, W1, (unsigned short*)XW, ei, GCUR, EBUF);

    // ---- per-bucket CSR finalize (+ POOL/CNT zero)
    csr_bucket<<<NBUCK, 256, 0, stream>>>(EBUF, GCUR, DEG, ROWP, dinv, COL, POOL);

    // ---- fused layer-1 agg + gemm2: XW1 -> (H1 in regs) -> XW2(bf16) in ACC; writes PCK
    agg1_gemm2<<<WAVE_NODE_BLK, 256, 0, stream>>>(ROWP, DEG, COL, dinv, PCK,
        (const unsigned short*)XW, b1, W2, (unsigned short*)ACC);

    // ---- layer 2 agg: XW2 -> H2(bf16) in XW
    agg_v4<<<WAVE_NODE_BLK, 256, 0, stream>>>(ROWP, DEG, dinv, PCK,
        (const unsigned short*)ACC, b2, (unsigned short*)XW, 1);

    // ---- layer 3 (reordered): Z = A_hat H2 -> bf16 in ACC -> pool -> small GEMM
    agg_v4<<<WAVE_NODE_BLK, 256, 0, stream>>>(ROWP, DEG, dinv, PCK,
        (const unsigned short*)XW, nullptr, (unsigned short*)ACC, 0);
    pool_seg<<<(N_NODES + 63) / 64, 256, 0, stream>>>((const unsigned short*)ACC,
        batch, POOL, CNT);
    out_gemm<<<N_GRAPHS / 4, 256, 0, stream>>>(POOL, CNT, W3, b3, out);
}

// Round 15
// 224.390 us; speedup vs baseline: 1.0887x; 1.0118x over previous
//
#include <hip/hip_runtime.h>
#include <hip/hip_bf16.h>
#include <hip/hip_fp16.h>

#define N_NODES 50000
#define N_EDGES 800000
#define CH 64
#define N_GRAPHS 256
#define NBUCK 196            // ceil(50000/256); bucket = dst >> 8
#define MAXB 4608            // padded bucket capacity (mean 4096, sigma~64)
#define NPAD (NBUCK * MAXB)  // 903168 padded edge slots
#define CHUNK 2048           // edges staged per scatter block
#define SCAT_BLK ((N_EDGES + CHUNK - 1) / CHUNK)   // 391
#define GEMM_BLK ((N_NODES + 31) / 32)             // 1563

__device__ __forceinline__ unsigned bf16_rne(float f) {
    unsigned u = __float_as_uint(f);
    return (u + 0x7fffu + ((u >> 16) & 1u)) >> 16;
}
__device__ __forceinline__ float4 ldtab(const unsigned short* __restrict__ tab, int s, int c4) {
    uint2 u = *(const uint2*)(tab + ((size_t)s << 6) + c4);
    float4 r;
    r.x = __uint_as_float(u.x << 16);
    r.y = __uint_as_float(u.x & 0xffff0000u);
    r.z = __uint_as_float(u.y << 16);
    r.w = __uint_as_float(u.y & 0xffff0000u);
    return r;
}
__device__ __forceinline__ unsigned pack_sn(int s, float n) {
    return (unsigned)s | ((unsigned)__half_as_ushort(__float2half_rn(n)) << 16);
}
__device__ __forceinline__ float unpack_n(unsigned p) {
    return __half2float(__ushort_as_half((unsigned short)(p >> 16)));
}

// ---------------- init: seed bucket cursors (1 block) ----------------
__global__ void init_k(int* __restrict__ gcur) {
    if (threadIdx.x < NBUCK) gcur[threadIdx.x] = threadIdx.x * MAXB;
}

// ---------------- fused: bin_scatter (blocks 0..390) || gemm1 (blocks 391..1953) ----------
union FusedSh {
    struct { float WT[64 * 68]; } g;                             // 17408 B
    struct {
        int hist[NBUCK]; int lofs[NBUCK]; int gbase[NBUCK]; int cur[NBUCK];
        int sc[256]; unsigned stage[CHUNK];
    } s;                                                         // 12352 B
};
__global__ __launch_bounds__(256) void gemm1_scatter(
        const float* __restrict__ x, const float* __restrict__ W1,
        unsigned short* __restrict__ xwout,
        const int* __restrict__ ei, int* __restrict__ gcur, unsigned* __restrict__ ebuf) {
    __shared__ FusedSh sh;
    int tid = threadIdx.x;
    if (blockIdx.x < SCAT_BLK) {
        // ---- scatter path ----
        for (int i = tid; i < NBUCK; i += 256) sh.s.hist[i] = 0;
        __syncthreads();
        int e0 = blockIdx.x * CHUNK;
        int n = min(CHUNK, N_EDGES - e0);
        int src[8], dst[8];
#pragma unroll
        for (int k = 0; k < 8; ++k) {
            int idx = k * 256 + tid;
            if (idx < n) {
                int e = e0 + idx;
                src[k] = ei[e];
                dst[k] = ei[N_EDGES + e];
                atomicAdd(&sh.s.hist[dst[k] >> 8], 1);
            } else dst[k] = -1;
        }
        __syncthreads();
        int v = (tid < NBUCK) ? sh.s.hist[tid] : 0;
        sh.s.sc[tid] = v;
        __syncthreads();
        for (int off = 1; off < 256; off <<= 1) {
            int t = (tid >= off) ? sh.s.sc[tid - off] : 0;
            __syncthreads();
            sh.s.sc[tid] += t;
            __syncthreads();
        }
        if (tid < NBUCK) {
            int ex = sh.s.sc[tid] - v;
            sh.s.lofs[tid] = ex;
            sh.s.cur[tid] = ex;
            sh.s.gbase[tid] = v ? atomicAdd(&gcur[tid], v) : 0;
        }
        __syncthreads();
#pragma unroll
        for (int k = 0; k < 8; ++k) {
            if (dst[k] >= 0) {
                int b = dst[k] >> 8;
                int p = atomicAdd(&sh.s.cur[b], 1);
                sh.s.stage[p] = (unsigned)src[k] | ((unsigned)(dst[k] & 255) << 16)
                                                | ((unsigned)b << 24);
            }
        }
        __syncthreads();
        for (int i = tid; i < n; i += 256) {
            unsigned p = sh.s.stage[i];
            int b = p >> 24;
            ebuf[sh.s.gbase[b] + (i - sh.s.lofs[b])] = p;   // contiguous per bucket
        }
    } else {
        // ---- gemm path (f32 input) ----
        for (int i = tid; i < 64 * 64; i += 256) {
            int k = i >> 6, c = i & 63;
            sh.g.WT[c * 68 + k] = W1[i];
        }
        __syncthreads();
        int lane = tid & 63;
        int wv = __builtin_amdgcn_readfirstlane(tid >> 6);
        int row0 = (blockIdx.x - SCAT_BLK) * 32 + wv * 8;
        if (row0 >= N_NODES) return;
        float acc[8] = {0.f, 0.f, 0.f, 0.f, 0.f, 0.f, 0.f, 0.f};
#pragma unroll 2
        for (int k = 0; k < 64; k += 4) {
            float4 w = *(const float4*)&sh.g.WT[lane * 68 + k];
#pragma unroll
            for (int r = 0; r < 8; ++r) {
                float4 xv = *(const float4*)&x[(size_t)(row0 + r) * 64 + k];  // scalar load
                acc[r] = fmaf(xv.x, w.x, acc[r]);
                acc[r] = fmaf(xv.y, w.y, acc[r]);
                acc[r] = fmaf(xv.z, w.z, acc[r]);
                acc[r] = fmaf(xv.w, w.w, acc[r]);
            }
        }
#pragma unroll
        for (int r = 0; r < 8; ++r)
            xwout[(size_t)(row0 + r) * 64 + lane] = (unsigned short)bf16_rne(acc[r]);
    }
}

// -------- per-bucket CSR build (deg, rowp, dinv, col) + POOL/CNT zero ----------
__global__ void csr_bucket(const unsigned* __restrict__ ebuf, const int* __restrict__ gcur,
                           int* __restrict__ deg, int* __restrict__ rowp,
                           float* __restrict__ dinv, int* __restrict__ col,
                           float* __restrict__ poolz) {
    __shared__ int nd[256];
    __shared__ int cur[256];
    __shared__ int sc[256];
    int b = blockIdx.x;
    int tid = threadIdx.x;
    {
        int zi = b * 85 + (tid % 85);
        if (tid < 85 && zi < N_GRAPHS * CH + N_GRAPHS) poolz[zi] = 0.0f;
    }
    nd[tid] = 0;
    __syncthreads();
    int es = b * MAXB, ee = gcur[b];
    for (int e = es + tid; e < ee; e += 256)
        atomicAdd(&nd[(ebuf[e] >> 16) & 255], 1);
    __syncthreads();
    int v = nd[tid];
    sc[tid] = v;
    __syncthreads();
    for (int off = 1; off < 256; off <<= 1) {
        int t = (tid >= off) ? sc[tid - off] : 0;
        __syncthreads();
        sc[tid] += t;
        __syncthreads();
    }
    int node = b * 256 + tid;
    int lstart = es + sc[tid] - v;
    if (node < N_NODES) {
        deg[node] = v;
        rowp[node] = lstart;
        dinv[node] = rsqrtf((float)v + 1.0f);
    }
    cur[tid] = lstart;
    __syncthreads();
    for (int e = es + tid; e < ee; e += 256) {
        unsigned p = ebuf[e];
        int pos = atomicAdd(&cur[(p >> 16) & 255], 1);
        col[pos] = (int)(p & 0xFFFFu);
    }
}

// ---- fused layer-1 agg + gemm2, LDS-free epilogue ----
// H1 = relu(agg(XW1)+b1) in regs; XW2 = H1@W2 with W2 read straight from L1
// and H1 redistributed via bf16-packed bpermutes (8 instead of 16)
__global__ void agg1_gemm2(const int* __restrict__ rowp, const int* __restrict__ deg,
                           const int* __restrict__ col, const float* __restrict__ dinv,
                           unsigned* __restrict__ pck,
                           const unsigned short* __restrict__ tab,
                           const float* __restrict__ b1, const float* __restrict__ W2,
                           unsigned short* __restrict__ xw2out) {
    int tid = threadIdx.x;
    int wv = __builtin_amdgcn_readfirstlane(tid >> 6);
    int node = blockIdx.x * 4 + wv;
    int lane = tid & 63;
    int q = lane >> 4;
    int c4 = (lane & 15) << 2;
    float dd = dinv[node];
    int cnt = deg[node];
    int start = rowp[node];
    float4 acc = make_float4(0.f, 0.f, 0.f, 0.f);
    if (q == 0) {
        float4 xs = ldtab(tab, node, c4);
        float dd2 = dd * dd;
        acc.x = xs.x * dd2; acc.y = xs.y * dd2; acc.z = xs.z * dd2; acc.w = xs.w * dd2;
    }
    int j = 0;
    for (; j + 16 <= cnt; j += 16) {
        int s[4]; float nv[4];
#pragma unroll
        for (int u = 0; u < 4; ++u) {
            int idx = start + j + 4 * u + q;
            s[u] = col[idx];
            nv[u] = dinv[s[u]] * dd;
            if ((lane & 15) == 0) pck[idx] = pack_sn(s[u], nv[u]);
        }
#pragma unroll
        for (int u = 0; u < 4; ++u) {
            float4 xv = ldtab(tab, s[u], c4);
            acc.x = fmaf(nv[u], xv.x, acc.x); acc.y = fmaf(nv[u], xv.y, acc.y);
            acc.z = fmaf(nv[u], xv.z, acc.z); acc.w = fmaf(nv[u], xv.w, acc.w);
        }
    }
    for (; j + 8 <= cnt; j += 8) {
        int s[2]; float nv[2];
#pragma unroll
        for (int u = 0; u < 2; ++u) {
            int idx = start + j + 4 * u + q;
            s[u] = col[idx];
            nv[u] = dinv[s[u]] * dd;
            if ((lane & 15) == 0) pck[idx] = pack_sn(s[u], nv[u]);
        }
#pragma unroll
        for (int u = 0; u < 2; ++u) {
            float4 xv = ldtab(tab, s[u], c4);
            acc.x = fmaf(nv[u], xv.x, acc.x); acc.y = fmaf(nv[u], xv.y, acc.y);
            acc.z = fmaf(nv[u], xv.z, acc.z); acc.w = fmaf(nv[u], xv.w, acc.w);
        }
    }
    for (; j < cnt; j += 4) {
        int jj = j + q;
        bool valid = jj < cnt;
        int s = col[start + (valid ? jj : 0)];
        float nv = valid ? dinv[s] * dd : 0.0f;
        if (valid && (lane & 15) == 0) pck[start + jj] = pack_sn(s, nv);
        float4 xv = ldtab(tab, s, c4);
        acc.x = fmaf(nv, xv.x, acc.x); acc.y = fmaf(nv, xv.y, acc.y);
        acc.z = fmaf(nv, xv.z, acc.z); acc.w = fmaf(nv, xv.w, acc.w);
    }
    acc.x += __shfl_xor(acc.x, 16); acc.y += __shfl_xor(acc.y, 16);
    acc.z += __shfl_xor(acc.z, 16); acc.w += __shfl_xor(acc.w, 16);
    acc.x += __shfl_xor(acc.x, 32); acc.y += __shfl_xor(acc.y, 32);
    acc.z += __shfl_xor(acc.z, 32); acc.w += __shfl_xor(acc.w, 32);
    // all lanes now hold the full H1 quad (c4..c4+3) = relu(acc + b1)
    {
        float4 bv = *(const float4*)&b1[c4];
        acc.x = fmaxf(acc.x + bv.x, 0.f); acc.y = fmaxf(acc.y + bv.y, 0.f);
        acc.z = fmaxf(acc.z + bv.z, 0.f); acc.w = fmaxf(acc.w + bv.w, 0.f);
    }
    // pack H1 quad to bf16 (matches old unfused precision; halves bpermute count)
    unsigned h0 = bf16_rne(acc.x) | (bf16_rne(acc.y) << 16);
    unsigned h1 = bf16_rne(acc.z) | (bf16_rne(acc.w) << 16);
    // epilogue GEMM: lane accumulates out[c4..c4+3] over k in [16q, 16q+16)
    float hq[16];
#pragma unroll
    for (int t = 0; t < 4; ++t) {
        int sl = 4 * q + t;                      // lane holding H1 quad for k=4*sl..+3
        unsigned v0 = (unsigned)__shfl((int)h0, sl, 64);
        unsigned v1 = (unsigned)__shfl((int)h1, sl, 64);
        hq[4 * t + 0] = __uint_as_float(v0 << 16);
        hq[4 * t + 1] = __uint_as_float(v0 & 0xffff0000u);
        hq[4 * t + 2] = __uint_as_float(v1 << 16);
        hq[4 * t + 3] = __uint_as_float(v1 & 0xffff0000u);
    }
    float4 g = make_float4(0.f, 0.f, 0.f, 0.f);
#pragma unroll
    for (int kk = 0; kk < 16; ++kk) {
        int k = 16 * q + kk;
        float4 wv = *(const float4*)&W2[(k << 6) + c4];   // global, L1-resident (16KB)
        g.x = fmaf(hq[kk], wv.x, g.x); g.y = fmaf(hq[kk], wv.y, g.y);
        g.z = fmaf(hq[kk], wv.z, g.z); g.w = fmaf(hq[kk], wv.w, g.w);
    }
    g.x += __shfl_xor(g.x, 16); g.y += __shfl_xor(g.y, 16);
    g.z += __shfl_xor(g.z, 16); g.w += __shfl_xor(g.w, 16);
    g.x += __shfl_xor(g.x, 32); g.y += __shfl_xor(g.y, 32);
    g.z += __shfl_xor(g.z, 32); g.w += __shfl_xor(g.w, 32);
    if (q == 0) {
        uint2 o;
        o.x = bf16_rne(g.x) | (bf16_rne(g.y) << 16);
        o.y = bf16_rne(g.z) | (bf16_rne(g.w) << 16);
        *(uint2*)&xw2out[((size_t)node << 6) + c4] = o;
    }
}

// ---------------- plain aggregation (layers 2-3), packed-edge stream ----------------
__global__ void agg_v4(const int* __restrict__ rowp, const int* __restrict__ deg,
                       const float* __restrict__ dinv, const unsigned* __restrict__ pck,
                       const unsigned short* __restrict__ tab, const float* __restrict__ bias,
                       unsigned short* __restrict__ outv, int do_relu) {
    int wv = __builtin_amdgcn_readfirstlane(threadIdx.x >> 6);
    int node = blockIdx.x * 4 + wv;
    int lane = threadIdx.x & 63;
    int q = lane >> 4;
    int c4 = (lane & 15) << 2;
    float dd = dinv[node];
    int cnt = deg[node];
    int start = rowp[node];
    float4 acc = make_float4(0.f, 0.f, 0.f, 0.f);
    if (q == 0) {
        float4 xs = ldtab(tab, node, c4);
        float dd2 = dd * dd;
        acc.x = xs.x * dd2; acc.y = xs.y * dd2; acc.z = xs.z * dd2; acc.w = xs.w * dd2;
    }
    int j = 0;
    for (; j + 16 <= cnt; j += 16) {
        int s[4]; float nv[4];
#pragma unroll
        for (int u = 0; u < 4; ++u) {
            unsigned p = pck[start + j + 4 * u + q];
            s[u] = (int)(p & 0xFFFFu);
            nv[u] = unpack_n(p);
        }
#pragma unroll
        for (int u = 0; u < 4; ++u) {
            float4 xv = ldtab(tab, s[u], c4);
            acc.x = fmaf(nv[u], xv.x, acc.x); acc.y = fmaf(nv[u], xv.y, acc.y);
            acc.z = fmaf(nv[u], xv.z, acc.z); acc.w = fmaf(nv[u], xv.w, acc.w);
        }
    }
    for (; j + 8 <= cnt; j += 8) {
        int s[2]; float nv[2];
#pragma unroll
        for (int u = 0; u < 2; ++u) {
            unsigned p = pck[start + j + 4 * u + q];
            s[u] = (int)(p & 0xFFFFu);
            nv[u] = unpack_n(p);
        }
#pragma unroll
        for (int u = 0; u < 2; ++u) {
            float4 xv = ldtab(tab, s[u], c4);
            acc.x = fmaf(nv[u], xv.x, acc.x); acc.y = fmaf(nv[u], xv.y, acc.y);
            acc.z = fmaf(nv[u], xv.z, acc.z); acc.w = fmaf(nv[u], xv.w, acc.w);
        }
    }
    for (; j < cnt; j += 4) {
        int jj = j + q;
        bool valid = jj < cnt;
        unsigned p = pck[start + (valid ? jj : 0)];
        int s = (int)(p & 0xFFFFu);
        float nv = valid ? unpack_n(p) : 0.0f;
        float4 xv = ldtab(tab, s, c4);
        acc.x = fmaf(nv, xv.x, acc.x); acc.y = fmaf(nv, xv.y, acc.y);
        acc.z = fmaf(nv, xv.z, acc.z); acc.w = fmaf(nv, xv.w, acc.w);
    }
    acc.x += __shfl_xor(acc.x, 16); acc.y += __shfl_xor(acc.y, 16);
    acc.z += __shfl_xor(acc.z, 16); acc.w += __shfl_xor(acc.w, 16);
    acc.x += __shfl_xor(acc.x, 32); acc.y += __shfl_xor(acc.y, 32);
    acc.z += __shfl_xor(acc.z, 32); acc.w += __shfl_xor(acc.w, 32);
    if (q == 0) {
        if (bias) {
            float4 bv = *(const float4*)&bias[c4];
            acc.x += bv.x; acc.y += bv.y; acc.z += bv.z; acc.w += bv.w;
        }
        if (do_relu) {
            acc.x = fmaxf(acc.x, 0.f); acc.y = fmaxf(acc.y, 0.f);
            acc.z = fmaxf(acc.z, 0.f); acc.w = fmaxf(acc.w, 0.f);
        }
        uint2 o;
        o.x = bf16_rne(acc.x) | (bf16_rne(acc.y) << 16);
        o.y = bf16_rne(acc.z) | (bf16_rne(acc.w) << 16);
        *(uint2*)&outv[((size_t)node << 6) + c4] = o;
    }
}

// ---------------- pool over bf16 Z (+ per-graph node count): batch sorted ----------------
__global__ void pool_seg(const unsigned short* __restrict__ h, const int* __restrict__ batch,
                         float* __restrict__ pool, float* __restrict__ cntg) {
    int ch = threadIdx.x & 63;
    int grp = threadIdx.x >> 6;
    int base = (blockIdx.x * 4 + grp) * 16;
    float acc = 0.0f;
    int curg = -1, runlen = 0;
    for (int n = 0; n < 16; ++n) {
        int node = base + n;
        if (node >= N_NODES) break;
        int g = batch[node];
        float v = __uint_as_float(((unsigned)h[((size_t)node << 6) + ch]) << 16);
        if (g != curg) {
            if (curg >= 0) {
                atomicAdd(&pool[curg * 64 + ch], acc);
                if (ch == 0) atomicAdd(&cntg[curg], (float)runlen);
            }
            curg = g; acc = v; runlen = 1;
        } else { acc += v; runlen++; }
    }
    if (curg >= 0) {
        atomicAdd(&pool[curg * 64 + ch], acc);
        if (ch == 0) atomicAdd(&cntg[curg], (float)runlen);
    }
}

// ---------------- tiny output GEMM: out = P @ W3 + cnt_g * b3 ----------------
__global__ void out_gemm(const float* __restrict__ P, const float* __restrict__ cntg,
                         const float* __restrict__ W, const float* __restrict__ b,
                         float* __restrict__ out) {
    __shared__ float Ws[64 * 64];
    int tid = threadIdx.x;
    for (int i = tid; i < 64 * 64; i += 256) Ws[i] = W[i];
    __syncthreads();
    int lane = tid & 63;
    int g = blockIdx.x * 4 + (tid >> 6);
    if (g >= N_GRAPHS) return;
    float pv = P[g * 64 + lane];
    float acc = 0.0f;
#pragma unroll
    for (int k = 0; k < 64; ++k)
        acc = fmaf(__shfl(pv, k, 64), Ws[k * 64 + lane], acc);
    out[g * 64 + lane] = acc + cntg[g] * b[lane];
}

extern "C" void kernel_launch(void* const* d_in, const int* in_sizes, int n_in,
                              void* d_out, int out_size, void* d_ws, size_t ws_size,
                              hipStream_t stream) {
    const float* x   = (const float*)d_in[0];
    const int* ei    = (const int*)d_in[1];   // int32 [2, N_EDGES]
    const int* batch = (const int*)d_in[2];   // int32 [N_NODES]
    const float* W1  = (const float*)d_in[3];
    const float* b1  = (const float*)d_in[4];
    const float* W2  = (const float*)d_in[5];
    const float* b2  = (const float*)d_in[6];
    const float* W3  = (const float*)d_in[7];
    const float* b3  = (const float*)d_in[8];
    float* out = (float*)d_out;

    // workspace layout (bytes), total ~37.1MB; PCK/COL/EBUF sized for NPAD=903168
    char* ws = (char*)d_ws;
    float*    dinv = (float*)(ws);                   // 50048 f32   -> ends   200192
    int*      DEG  = (int*)(ws + 200192);            // 50048 i32   -> ends   400384
    int*      ROWP = (int*)(ws + 400384);            // 50048 i32   -> ends   600576
    int*      COL  = (int*)(ws + 600576);            // NPAD i32    -> ends  4213248
    unsigned* PCK  = (unsigned*)(ws + 4213248);      // NPAD u32    -> ends  7825920
    float*    XW   = (float*)(ws + 7825920);         // 12.8MB      -> ends 20625920
    float*    ACC  = (float*)(ws + 20625920);        // 12.8MB      -> ends 33425920
    float*    POOL = (float*)(ws + 33425920);        // 16384 f32   -> ends 33491456
    float*    CNT  = (float*)(ws + 33491456);        // 256 f32 (contiguous after POOL)
    int*      GCUR = (int*)(ws + 33492480);          // 196 i32
    unsigned* EBUF = (unsigned*)(ws + 33493504);     // NPAD u32    -> ends 37106176

    const int WAVE_NODE_BLK = N_NODES / 4;           // 12500 (exact)

    // ---- init bucket cursors
    init_k<<<1, 256, 0, stream>>>(GCUR);

    // ---- fused: edge bin-scatter (391 blks) || gemm1 x@W1->XW1 bf16 (1563 blks)
    gemm1_scatter<<<SCAT_BLK + GEMM_BLK, 256, 0, stream>>>(
        x, W1, (unsigned short*)XW, ei, GCUR, EBUF);

    // ---- per-bucket CSR finalize (+ POOL/CNT zero)
    csr_bucket<<<NBUCK, 256, 0, stream>>>(EBUF, GCUR, DEG, ROWP, dinv, COL, POOL);

    // ---- fused layer-1 agg + gemm2 (LDS-free): XW1 -> (H1 regs) -> XW2(bf16) in ACC
    agg1_gemm2<<<WAVE_NODE_BLK, 256, 0, stream>>>(ROWP, DEG, COL, dinv, PCK,
        (const unsigned short*)XW, b1, W2, (unsigned short*)ACC);

    // ---- layer 2 agg: XW2 -> H2(bf16) in XW
    agg_v4<<<WAVE_NODE_BLK, 256, 0, stream>>>(ROWP, DEG, dinv, PCK,
        (const unsigned short*)ACC, b2, (unsigned short*)XW, 1);

    // ---- layer 3 (reordered): Z = A_hat H2 -> bf16 in ACC -> pool -> small GEMM
    agg_v4<<<WAVE_NODE_BLK, 256, 0, stream>>>(ROWP, DEG, dinv, PCK,
        (const unsigned short*)XW, nullptr, (unsigned short*)ACC, 0);
    pool_seg<<<(N_NODES + 63) / 64, 256, 0, stream>>>((const unsigned short*)ACC,
        batch, POOL, CNT);
    out_gemm<<<N_GRAPHS / 4, 256, 0, stream>>>(POOL, CNT, W3, b3, out);
}